// Round 2
// baseline (265.532 us; speedup 1.0000x reference)
//
#include <hip/hip_runtime.h>

// HierarchicalMultinomialRegression: fused fixed-effects GEMV + per-row AR(1)
// recurrence replay + gather. Never materializes u (B,L,T,Km1).
//
// Round 2 changes vs round 1:
//  - __launch_bounds__(256, 4): cap VGPR at 128 (was 256) -> 4x occupancy.
//  - LDS-staged outputs, written as dense stride-1 coalesced stores: kills
//    the 7.3x HBM write amplification from strided partial-sector stores.
//
// Inputs (setup_inputs dict order):
//  0: X         (N, 64)        f32
//  1: beta      (64, 7)        f32
//  2: raw_rho   (7, 7)         f32   (L, Km1)
//  3: raw_chol  (7, 7, 7)      f32   (Km1, L, L), lower-tri
//  4: eps       (B, 7, 20, 7)  f32   (B, L, T, Km1)
//  5: batter_ids (N,) i32
//  6: league_ids (N,) i32
//  7: season_ids (N,) i32
// Output: logits (N,8) then eps_sample (N,7), concatenated flat, f32.

#define NF 64
#define LDIM 7
#define TDIM 20
#define KM1 7
#define BLOCK 256

__global__ __launch_bounds__(BLOCK, 4) void hmr_kernel(
    const float* __restrict__ X,
    const float* __restrict__ beta,
    const float* __restrict__ raw_rho,
    const float* __restrict__ raw_chol,
    const float* __restrict__ eps,
    const int* __restrict__ batter_ids,
    const int* __restrict__ league_ids,
    const int* __restrict__ season_ids,
    float* __restrict__ out,
    int n_total)
{
    // small constants
    __shared__ float s_beta[NF * KM1];      // beta[j][k], broadcast access
    __shared__ float s_rho[LDIM][KM1];      // tanh(raw_rho)
    __shared__ float s_sd[LDIM][KM1];       // scaling[l][k] * chol[k][l][l]
    __shared__ float s_M[KM1][LDIM];        // M[k][j] = sum_i chol[k][i][j]
    // output staging (row-major, mirrors global layout)
    __shared__ float s_log[BLOCK * 8];
    __shared__ float s_es[BLOCK * KM1];

    const int tid = threadIdx.x;

    for (int i = tid; i < NF * KM1; i += BLOCK) s_beta[i] = beta[i];

    if (tid < LDIM * KM1) {
        const int l = tid / KM1, k = tid % KM1;
        const float r = tanhf(raw_rho[l * KM1 + k]);
        s_rho[l][k] = r;
        const float scal = 1.0f / sqrtf(1.0f - r * r);
        s_sd[l][k] = scal * raw_chol[k * (LDIM * LDIM) + l * LDIM + l];
        // same 7x7 index space reused for M
        const int k2 = l, j = k;
        float m = 0.f;
        #pragma unroll
        for (int i = 0; i < LDIM; ++i)
            m += raw_chol[k2 * (LDIM * LDIM) + i * LDIM + j];
        s_M[k2][j] = m;
    }
    __syncthreads();

    const int bstart = blockIdx.x * BLOCK;
    const int n = bstart + tid;
    const bool active = (n < n_total);

    if (active) {
        const int b = batter_ids[n];
        const int l = league_ids[n];
        const int t = season_ids[n];

        // ---- fixed effects: acc[k] = sum_j X[n,j] * beta[j,k] ----
        float acc[KM1];
        #pragma unroll
        for (int k = 0; k < KM1; ++k) acc[k] = 0.f;

        const float4* __restrict__ xrow =
            reinterpret_cast<const float4*>(X + (long)n * NF);
        #pragma unroll
        for (int j4 = 0; j4 < NF / 4; ++j4) {
            const float4 x = xrow[j4];
            const float* b0 = &s_beta[(j4 * 4 + 0) * KM1];
            const float* b1 = &s_beta[(j4 * 4 + 1) * KM1];
            const float* b2 = &s_beta[(j4 * 4 + 2) * KM1];
            const float* b3 = &s_beta[(j4 * 4 + 3) * KM1];
            #pragma unroll
            for (int k = 0; k < KM1; ++k)
                acc[k] += x.x * b0[k] + x.y * b1[k] + x.z * b2[k] + x.w * b3[k];
        }

        // ---- AR(1) recurrence replay up to t ----
        const float* __restrict__ erow = eps + ((long)b * LDIM + l) * (TDIM * KM1);

        float u[KM1];
        #pragma unroll
        for (int k = 0; k < KM1; ++k) u[k] = s_sd[l][k] * erow[k];

        for (int s = 1; s <= t; ++s) {
            float e[KM1];
            #pragma unroll
            for (int k = 0; k < KM1; ++k) e[k] = erow[s * KM1 + k];
            float nz[KM1];
            #pragma unroll
            for (int j = 0; j < KM1; ++j) {
                float m = 0.f;
                #pragma unroll
                for (int k = 0; k < KM1; ++k) m += e[k] * s_M[k][j];
                nz[j] = m;
            }
            #pragma unroll
            for (int j = 0; j < KM1; ++j)
                u[j] = s_rho[l][j] * u[j] + nz[j];
        }

        // ---- stage outputs in LDS (row-major, same as global layout) ----
        s_log[tid * 8 + 0] = 0.f;
        #pragma unroll
        for (int k = 0; k < KM1; ++k) s_log[tid * 8 + 1 + k] = acc[k] + u[k];
        #pragma unroll
        for (int k = 0; k < KM1; ++k) s_es[tid * KM1 + k] = erow[t * KM1 + k];
    }
    __syncthreads();

    // ---- dense coalesced writes: full cachelines per wave store ----
    const int rows = min(BLOCK, n_total - bstart);

    // logits region: rows*8 floats, contiguous, 32B-aligned (bstart*8*4)
    {
        float* dst = out + (long)bstart * 8;
        const int cnt = rows * 8;           // multiple of 8 -> of 4
        const int c4 = cnt / 4;
        const float4* src4 = reinterpret_cast<const float4*>(s_log);
        float4* dst4 = reinterpret_cast<float4*>(dst);
        for (int i = tid; i < c4; i += BLOCK) dst4[i] = src4[i];
    }
    // eps_sample region: rows*7 floats, contiguous
    {
        float* dst = out + (long)n_total * 8 + (long)bstart * KM1;
        const int cnt = rows * KM1;
        const int c4 = cnt / 4;
        // base is only 4B-aligned in general (n_total*8 is, bstart*7*4 is 28B
        // stride) -> use float4 only if 16B-aligned, else dword loop.
        if ((((long)n_total * 8 + (long)bstart * KM1) & 3) == 0) {
            const float4* src4 = reinterpret_cast<const float4*>(s_es);
            float4* dst4 = reinterpret_cast<float4*>(dst);
            for (int i = tid; i < c4; i += BLOCK) dst4[i] = src4[i];
            for (int i = c4 * 4 + tid; i < cnt; i += BLOCK) dst[i] = s_es[i];
        } else {
            for (int i = tid; i < cnt; i += BLOCK) dst[i] = s_es[i];
        }
    }
}

extern "C" void kernel_launch(void* const* d_in, const int* in_sizes, int n_in,
                              void* d_out, int out_size, void* d_ws, size_t ws_size,
                              hipStream_t stream)
{
    const float* X        = (const float*)d_in[0];
    const float* beta     = (const float*)d_in[1];
    const float* raw_rho  = (const float*)d_in[2];
    const float* raw_chol = (const float*)d_in[3];
    const float* eps      = (const float*)d_in[4];
    const int* batter_ids = (const int*)d_in[5];
    const int* league_ids = (const int*)d_in[6];
    const int* season_ids = (const int*)d_in[7];
    float* out = (float*)d_out;

    const int n_total = in_sizes[5];  // N = 200000
    const int grid = (n_total + BLOCK - 1) / BLOCK;

    hmr_kernel<<<grid, BLOCK, 0, stream>>>(X, beta, raw_rho, raw_chol, eps,
                                           batter_ids, league_ids, season_ids,
                                           out, n_total);
}

// Round 3
// 47.460 us; speedup vs baseline: 5.5948x; 5.5948x over previous
//
#include <hip/hip_runtime.h>

// HierarchicalMultinomialRegression: fused fixed-effects GEMV + per-row AR(1)
// recurrence replay + gather. Never materializes u (B,L,T,Km1).
//
// Round 3 changes:
//  - launch_bounds(256,3) (cap ~168 VGPR) + unroll-4 GEMV: round 2's (256,4)
//    clamped to 64 VGPR and spilled ~1KB/thread to scratch (FETCH +210MB,
//    WRITE +300MB). Natural pressure here ~90 regs -> no spill, 3+ waves/EU.
//  - LDS output staging with pad-9 rows (stride 9 coprime to 32 banks ->
//    conflict-free writes), dense stride-1 coalesced global stores: kills
//    round 1's 7x write amplification (85MB -> ~13MB).
//  - eps_sample kept in registers from the recurrence's last load (saves
//    7 loads/thread).
//
// Inputs (setup_inputs dict order):
//  0: X         (N, 64)        f32
//  1: beta      (64, 7)        f32
//  2: raw_rho   (7, 7)         f32   (L, Km1)
//  3: raw_chol  (7, 7, 7)      f32   (Km1, L, L), lower-tri
//  4: eps       (B, 7, 20, 7)  f32   (B, L, T, Km1)
//  5: batter_ids (N,) i32
//  6: league_ids (N,) i32
//  7: season_ids (N,) i32
// Output: logits (N,8) then eps_sample (N,7), concatenated flat, f32.

#define NF 64
#define LDIM 7
#define TDIM 20
#define KM1 7
#define BLOCK 256
#define PAD 9   // padded LDS row stride (floats); 9 coprime to 32 banks

__global__ __launch_bounds__(BLOCK, 3) void hmr_kernel(
    const float* __restrict__ X,
    const float* __restrict__ beta,
    const float* __restrict__ raw_rho,
    const float* __restrict__ raw_chol,
    const float* __restrict__ eps,
    const int* __restrict__ batter_ids,
    const int* __restrict__ league_ids,
    const int* __restrict__ season_ids,
    float* __restrict__ out,
    int n_total)
{
    // small constants
    __shared__ float s_beta[NF * KM1];      // beta[j][k], broadcast access
    __shared__ float s_rho[LDIM][KM1];      // tanh(raw_rho)
    __shared__ float s_sd[LDIM][KM1];       // scaling[l][k] * chol[k][l][l]
    __shared__ float s_M[KM1][LDIM];        // M[k][j] = sum_i chol[k][i][j]
    // output staging, padded rows (conflict-free: stride 9 floats)
    __shared__ float s_log[BLOCK * PAD];
    __shared__ float s_es[BLOCK * PAD];

    const int tid = threadIdx.x;

    for (int i = tid; i < NF * KM1; i += BLOCK) s_beta[i] = beta[i];

    if (tid < LDIM * KM1) {
        const int l = tid / KM1, k = tid % KM1;
        const float r = tanhf(raw_rho[l * KM1 + k]);
        s_rho[l][k] = r;
        const float scal = 1.0f / sqrtf(1.0f - r * r);
        s_sd[l][k] = scal * raw_chol[k * (LDIM * LDIM) + l * LDIM + l];
        // same 7x7 index space reused for M
        const int k2 = l, j = k;
        float m = 0.f;
        #pragma unroll
        for (int i = 0; i < LDIM; ++i)
            m += raw_chol[k2 * (LDIM * LDIM) + i * LDIM + j];
        s_M[k2][j] = m;
    }
    __syncthreads();

    const int bstart = blockIdx.x * BLOCK;
    const int n = bstart + tid;

    if (n < n_total) {
        const int b = batter_ids[n];
        const int l = league_ids[n];
        const int t = season_ids[n];

        // ---- fixed effects: acc[k] = sum_j X[n,j] * beta[j,k] ----
        float acc[KM1];
        #pragma unroll
        for (int k = 0; k < KM1; ++k) acc[k] = 0.f;

        const float4* __restrict__ xrow =
            reinterpret_cast<const float4*>(X + (long)n * NF);
        #pragma unroll 4
        for (int j4 = 0; j4 < NF / 4; ++j4) {
            const float4 x = xrow[j4];
            const float* b0 = &s_beta[(j4 * 4 + 0) * KM1];
            const float* b1 = &s_beta[(j4 * 4 + 1) * KM1];
            const float* b2 = &s_beta[(j4 * 4 + 2) * KM1];
            const float* b3 = &s_beta[(j4 * 4 + 3) * KM1];
            #pragma unroll
            for (int k = 0; k < KM1; ++k)
                acc[k] += x.x * b0[k] + x.y * b1[k] + x.z * b2[k] + x.w * b3[k];
        }

        // ---- AR(1) recurrence replay up to t ----
        const float* __restrict__ erow = eps + ((long)b * LDIM + l) * (TDIM * KM1);

        float last_e[KM1];   // raw eps at current timestep (becomes eps_sample)
        float u[KM1];
        #pragma unroll
        for (int k = 0; k < KM1; ++k) {
            last_e[k] = erow[k];
            u[k] = s_sd[l][k] * last_e[k];
        }

        for (int s = 1; s <= t; ++s) {
            #pragma unroll
            for (int k = 0; k < KM1; ++k) last_e[k] = erow[s * KM1 + k];
            float nz[KM1];
            #pragma unroll
            for (int j = 0; j < KM1; ++j) {
                float m = 0.f;
                #pragma unroll
                for (int k = 0; k < KM1; ++k) m += last_e[k] * s_M[k][j];
                nz[j] = m;
            }
            #pragma unroll
            for (int j = 0; j < KM1; ++j)
                u[j] = s_rho[l][j] * u[j] + nz[j];
        }

        // ---- stage outputs in padded LDS rows (conflict-free) ----
        s_log[tid * PAD + 0] = 0.f;
        #pragma unroll
        for (int k = 0; k < KM1; ++k) s_log[tid * PAD + 1 + k] = acc[k] + u[k];
        #pragma unroll
        for (int k = 0; k < KM1; ++k) s_es[tid * PAD + k] = last_e[k];
    }
    __syncthreads();

    // ---- dense, fully-coalesced global writes (stride-1 across lanes) ----
    const int rows = min(BLOCK, n_total - bstart);

    {   // logits region: rows*8 contiguous floats
        float* __restrict__ dst = out + (long)bstart * 8;
        const int cnt = rows * 8;
        for (int i = tid; i < cnt; i += BLOCK) {
            const int r = i >> 3, c = i & 7;
            dst[i] = s_log[r * PAD + c];
        }
    }
    {   // eps_sample region: rows*7 contiguous floats
        float* __restrict__ dst = out + (long)n_total * 8 + (long)bstart * KM1;
        const int cnt = rows * KM1;
        for (int i = tid; i < cnt; i += BLOCK) {
            const int r = i / KM1, c = i - r * KM1;
            dst[i] = s_es[r * PAD + c];
        }
    }
}

extern "C" void kernel_launch(void* const* d_in, const int* in_sizes, int n_in,
                              void* d_out, int out_size, void* d_ws, size_t ws_size,
                              hipStream_t stream)
{
    const float* X        = (const float*)d_in[0];
    const float* beta     = (const float*)d_in[1];
    const float* raw_rho  = (const float*)d_in[2];
    const float* raw_chol = (const float*)d_in[3];
    const float* eps      = (const float*)d_in[4];
    const int* batter_ids = (const int*)d_in[5];
    const int* league_ids = (const int*)d_in[6];
    const int* season_ids = (const int*)d_in[7];
    float* out = (float*)d_out;

    const int n_total = in_sizes[5];  // N = 200000
    const int grid = (n_total + BLOCK - 1) / BLOCK;

    hmr_kernel<<<grid, BLOCK, 0, stream>>>(X, beta, raw_rho, raw_chol, eps,
                                           batter_ids, league_ids, season_ids,
                                           out, n_total);
}